// Round 20
// baseline (665.998 us; speedup 1.0000x reference)
//
#include <hip/hip_runtime.h>
#include <math.h>

#define VOCAB 32000
#define D_IN  256
#define D_H   32
#define B_SZ  16
#define S_LEN 512
#define NTOK  (B_SZ * S_LEN)   // 8192
#define NV1   25               // vocab splits in sum pass
#define VT1   (VOCAB / 16 / NV1)   // 80 tiles of 16 rows
#define NV2   25               // vocab splits in out pass
#define VT2   (VOCAB / 16 / NV2)   // 80 tiles
#define EMB_BLKS (NTOK / 4)            // 2048
#define CVT_BLKS (VOCAB * D_H / 512)   // 2000

typedef __bf16 bf16;
typedef __attribute__((ext_vector_type(8))) __bf16 bf16x8;
typedef __attribute__((ext_vector_type(4))) __bf16 bf16x4;
typedef __attribute__((ext_vector_type(4))) float f32x4;

__device__ __forceinline__ float rcpf(float x) {
    return __builtin_amdgcn_rcpf(x);
}

__device__ __forceinline__ float sigf(float x) {
    return rcpf(1.0f + __expf(-x));
}

__device__ __forceinline__ float tanhfast(float x) {
    float ax = fabsf(x);
    float e = __expf(-2.0f * ax);
    float r = (1.0f - e) * rcpf(1.0f + e);
    return copysignf(r, x);
}

__device__ __forceinline__ float dot4(float4 a, float4 b) {
    return a.x * b.x + a.y * b.y + a.z * b.z + a.w * b.w;
}

// LDS-only barrier: waits LDS ops, does NOT drain vmem (global prefetch
// loads / flush stores stay in flight across it).
__device__ __forceinline__ void lds_barrier() {
    asm volatile("s_waitcnt lgkmcnt(0)" ::: "memory");
    __builtin_amdgcn_s_barrier();
    asm volatile("" ::: "memory");
}

// ---------------------------------------------------------------------------
// Kernel A (merged): blocks [0, EMB_BLKS) = input-gate pack;
// blocks [EMB_BLKS, EMB_BLKS+CVT_BLKS) = W_fc -> bf16 hi/lo split.
// ---------------------------------------------------------------------------
__global__ __launch_bounds__(128) void k_embed_cvt(
    const int* __restrict__ x_ids, const float* __restrict__ emb,
    const float* __restrict__ W_ih1, const float* __restrict__ b_ih1,
    const float* __restrict__ b_hh1, float* __restrict__ G1d,
    const float* __restrict__ W_fc, bf16* __restrict__ Whi,
    bf16* __restrict__ Wlo)
{
    if (blockIdx.x >= EMB_BLKS) {
        const long i = ((long)(blockIdx.x - EMB_BLKS) * 128 + threadIdx.x) * 4;
        float4 w = *(const float4*)(W_fc + i);
        bf16 h0 = (bf16)w.x, h1 = (bf16)w.y, h2 = (bf16)w.z, h3 = (bf16)w.w;
        bf16x4 hv = {h0, h1, h2, h3};
        bf16x4 lv = {(bf16)(w.x - (float)h0), (bf16)(w.y - (float)h1),
                     (bf16)(w.z - (float)h2), (bf16)(w.w - (float)h3)};
        *(bf16x4*)(Whi + i) = hv;
        *(bf16x4*)(Wlo + i) = lv;
        return;
    }

    __shared__ float4 xs[4][64];
    const int tid = threadIdx.x;
    const int t0  = blockIdx.x * 4;
    const int r0  = tid >> 6, j = tid & 63;
    #pragma unroll
    for (int rr = 0; rr < 2; ++rr) {
        int r = rr * 2 + r0;
        long id = x_ids[t0 + r];
        xs[r][j] = ((const float4*)(emb + id * (long)D_IN))[j];
    }
    __syncthreads();

    const int g = tid;
    const float4* wrow = (const float4*)(W_ih1 + (long)g * D_IN);
    const float bias = b_ih1[g] + b_hh1[g];
    float a0 = bias, a1 = bias, a2 = bias, a3 = bias;
    #pragma unroll 8
    for (int jj = 0; jj < 64; ++jj) {
        float4 w = wrow[jj];
        a0 += dot4(w, xs[0][jj]);
        a1 += dot4(w, xs[1][jj]);
        a2 += dot4(w, xs[2][jj]);
        a3 += dot4(w, xs[3][jj]);
    }
    const int b  = t0 >> 9;
    const int s0 = t0 & 511;
    const int gt = g >> 5;
    const int u  = g & 31;
    const int w  = u >> 2;
    const int lq = u & 3;
    const int lane = lq * 16 + b;
    float vals[4] = {a0, a1, a2, a3};
    #pragma unroll
    for (int k = 0; k < 4; ++k) {
        G1d[(((long)(s0 + k) * 8 + w) * 64 + lane) * 4 + gt] = vals[k];
    }
}

// ---------------------------------------------------------------------------
// Kernel B: MFMA LSTM v7 = v6 + lgkmcnt-only barriers (no per-step vmem
// drain). 3 MFMAs/step, bf16 recurrence; stored h2 keeps full hi/lo.
// ---------------------------------------------------------------------------
__global__ __launch_bounds__(512, 1) void k_lstm_mfma(
    const float* __restrict__ G1d,
    const float* __restrict__ W_hh1,
    const float* __restrict__ W_ih2, const float* __restrict__ W_hh2,
    const float* __restrict__ b_ih2, const float* __restrict__ b_hh2,
    bf16* __restrict__ Hhi, bf16* __restrict__ Hlo)
{
    __shared__ alignas(16) bf16 H1h[2][16][40];
    __shared__ alignas(16) bf16 H2h[2][16][40];
    __shared__ alignas(16) float ring[2][16][16][36];   // 72 KB

    const int t  = threadIdx.x;
    const int w  = t >> 6;
    const int l  = t & 63;
    const int lr = l & 15, lq = l >> 4;

    const int garow = (lr & 3) * 32 + 4 * w + (lr >> 2);
    bf16x8 w1h, wi2h, wh2h;
    #pragma unroll
    for (int j = 0; j < 8; ++j) {
        w1h[j]  = (bf16)W_hh1[garow * D_H + lq * 8 + j];
        wi2h[j] = (bf16)W_ih2[garow * D_H + lq * 8 + j];
        wh2h[j] = (bf16)W_hh2[garow * D_H + lq * 8 + j];
    }

    const int u = 4 * w + lq;      // this lane's cell unit; batch = lr
    f32x4 bias2;
    #pragma unroll
    for (int r = 0; r < 4; ++r)
        bias2[r] = b_ih2[r * 32 + u] + b_hh2[r * 32 + u];

    bf16x8 h1fh, h2fh;
    #pragma unroll
    for (int j = 0; j < 8; ++j) {
        h1fh[j] = (bf16)0.0f; h2fh[j] = (bf16)0.0f;
    }
    float c1 = 0.0f, c2 = 0.0f;

    const f32x4* G1v = (const f32x4*)G1d;

    // flush chunk cc (steps 16cc..16cc+15) from ring to Hhi/Hlo as hi/lo bf16
    auto flush_chunk = [&](int cc) {
        const int rp   = cc & 1;
        const int pair = t >> 1;
        const int ss   = pair >> 4;
        const int bb   = pair & 15;
        const int u0   = (t & 1) * 16;
        const float* src = &ring[rp][ss][bb][u0];
        const long gbase = ((long)bb * S_LEN + cc * 16 + ss) * D_H + u0;
        #pragma unroll
        for (int q = 0; q < 4; ++q) {
            float4 v = *(const float4*)(src + q * 4);
            bf16 e0 = (bf16)v.x, e1 = (bf16)v.y, e2 = (bf16)v.z, e3 = (bf16)v.w;
            bf16x4 hv = {e0, e1, e2, e3};
            bf16x4 lv = {(bf16)(v.x - (float)e0), (bf16)(v.y - (float)e1),
                         (bf16)(v.z - (float)e2), (bf16)(v.w - (float)e3)};
            *(bf16x4*)(Hhi + gbase + q * 4) = hv;
            *(bf16x4*)(Hlo + gbase + q * 4) = lv;
        }
    };

    // one LSTM step: L1(s) + L2(s-1), 1 LDS-only barrier, 3 MFMAs
    auto step = [&](int s, f32x4 g1c) {
        f32x4 d = __builtin_amdgcn_mfma_f32_16x16x32_bf16(w1h, h1fh, g1c, 0, 0, 0);

        f32x4 e;
        if (s > 0) {
            e = __builtin_amdgcn_mfma_f32_16x16x32_bf16(wi2h, h1fh, bias2, 0, 0, 0);
            e = __builtin_amdgcn_mfma_f32_16x16x32_bf16(wh2h, h2fh, e, 0, 0, 0);
        }

        {
            float iv = sigf(d[0]), fv = sigf(d[1]);
            float gv = tanhfast(d[2]), ov = sigf(d[3]);
            c1 = fv * c1 + iv * gv;
            float h1 = ov * tanhfast(c1);
            H1h[s & 1][lr][u] = (bf16)h1;
        }

        if (s > 0) {
            float iv = sigf(e[0]), fv = sigf(e[1]);
            float gv = tanhfast(e[2]), ov = sigf(e[3]);
            c2 = fv * c2 + iv * gv;
            float h2 = ov * tanhfast(c2);
            H2h[(s - 1) & 1][lr][u] = (bf16)h2;
            ring[((s - 1) >> 4) & 1][(s - 1) & 15][lr][u] = h2;
        }
        lds_barrier();

        h1fh = *(const bf16x8*)&H1h[s & 1][lr][lq * 8];
        if (s > 0) {
            h2fh = *(const bf16x8*)&H2h[(s - 1) & 1][lr][lq * 8];
        }

        if ((s & 15) == 0 && s > 0) {
            flush_chunk((s >> 4) - 1);
        }
    };

    // ---- chunked G1 staging: 64 chunks of 8 steps, double-buffered ----
    f32x4 bufA[8], bufB[8];
    #pragma unroll
    for (int k = 0; k < 8; ++k)
        bufA[k] = G1v[((long)k * 8 + w) * 64 + l];

    #pragma unroll 1
    for (int c = 0; c < 64; c += 2) {
        {   // even chunk: compute from bufA, prefetch chunk c+1 into bufB
            const int cn = c + 1;
            #pragma unroll
            for (int k = 0; k < 8; ++k)
                bufB[k] = G1v[((long)(cn * 8 + k) * 8 + w) * 64 + l];
            #pragma unroll
            for (int k = 0; k < 8; ++k)
                step(c * 8 + k, bufA[k]);
        }
        {   // odd chunk: compute from bufB, prefetch chunk c+2 into bufA
            const int cn = (c + 2 < 64) ? c + 2 : 0;
            #pragma unroll
            for (int k = 0; k < 8; ++k)
                bufA[k] = G1v[((long)(cn * 8 + k) * 8 + w) * 64 + l];
            #pragma unroll
            for (int k = 0; k < 8; ++k)
                step((c + 1) * 8 + k, bufB[k]);
        }
    }

    // ---- epilogue: L2(S_LEN-1) ----
    {
        f32x4 e = __builtin_amdgcn_mfma_f32_16x16x32_bf16(wi2h, h1fh, bias2, 0, 0, 0);
        e = __builtin_amdgcn_mfma_f32_16x16x32_bf16(wh2h, h2fh, e, 0, 0, 0);
        float iv = sigf(e[0]), fv = sigf(e[1]);
        float gv = tanhfast(e[2]), ov = sigf(e[3]);
        c2 = fv * c2 + iv * gv;
        float h2 = ov * tanhfast(c2);
        ring[((S_LEN - 1) >> 4) & 1][(S_LEN - 1) & 15][lr][u] = h2;
    }
    __syncthreads();
    flush_chunk((S_LEN >> 4) - 1);       // steps 496..511
}

// ---------------------------------------------------------------------------
// Kernel C1 (MFMA): partial softmax denominators.
// ---------------------------------------------------------------------------
__global__ __launch_bounds__(256) void k_fc_sum(
    const bf16* __restrict__ Hhi, const bf16* __restrict__ Hlo,
    const bf16* __restrict__ Whi, const bf16* __restrict__ Wlo,
    const float* __restrict__ b_fc, float* __restrict__ partial)
{
    const int lane = threadIdx.x & 63;
    const int wid  = threadIdx.x >> 6;
    const int tg   = blockIdx.x / NV1;
    const int nv   = blockIdx.x % NV1;
    const int t0   = tg * 128 + wid * 32;
    const int lr   = lane & 15, lq = lane >> 4;

    const long arow0 = (long)(t0 + lr) * D_H + lq * 8;
    const long arow1 = arow0 + 16 * D_H;
    bf16x8 a0h = *(const bf16x8*)(Hhi + arow0);
    bf16x8 a0l = *(const bf16x8*)(Hlo + arow0);
    bf16x8 a1h = *(const bf16x8*)(Hhi + arow1);
    bf16x8 a1l = *(const bf16x8*)(Hlo + arow1);

    f32x4 acc0 = {0.f, 0.f, 0.f, 0.f}, acc1 = {0.f, 0.f, 0.f, 0.f};
    const f32x4 z = {0.f, 0.f, 0.f, 0.f};
    int v0 = nv * (VOCAB / NV1);
    for (int tile = 0; tile < VT1; ++tile, v0 += 16) {
        const long brow = (long)(v0 + lr) * D_H + lq * 8;
        bf16x8 bh = *(const bf16x8*)(Whi + brow);
        bf16x8 bl = *(const bf16x8*)(Wlo + brow);
        float bias = b_fc[v0 + lr];
        f32x4 d0 = __builtin_amdgcn_mfma_f32_16x16x32_bf16(a0h, bh, z, 0, 0, 0);
        d0 = __builtin_amdgcn_mfma_f32_16x16x32_bf16(a0l, bh, d0, 0, 0, 0);
        d0 = __builtin_amdgcn_mfma_f32_16x16x32_bf16(a0h, bl, d0, 0, 0, 0);
        f32x4 d1 = __builtin_amdgcn_mfma_f32_16x16x32_bf16(a1h, bh, z, 0, 0, 0);
        d1 = __builtin_amdgcn_mfma_f32_16x16x32_bf16(a1l, bh, d1, 0, 0, 0);
        d1 = __builtin_amdgcn_mfma_f32_16x16x32_bf16(a1h, bl, d1, 0, 0, 0);
        #pragma unroll
        for (int r = 0; r < 4; ++r) {
            acc0[r] += __expf(d0[r] + bias);
            acc1[r] += __expf(d1[r] + bias);
        }
    }

    #pragma unroll
    for (int m = 1; m < 16; m <<= 1) {
        #pragma unroll
        for (int r = 0; r < 4; ++r) {
            acc0[r] += __shfl_xor(acc0[r], m, 64);
            acc1[r] += __shfl_xor(acc1[r], m, 64);
        }
    }
    if (lr == 0) {
        #pragma unroll
        for (int r = 0; r < 4; ++r) {
            partial[(long)nv * NTOK + t0 + lq * 4 + r]      = acc0[r];
            partial[(long)nv * NTOK + t0 + 16 + lq * 4 + r] = acc1[r];
        }
    }
}

// ---------------------------------------------------------------------------
// Kernel C2 (MFMA): recompute logits, write normalized softmax.
// Per-token 1/sum is recomputed from `partial` in-block (k_inv removed).
// ---------------------------------------------------------------------------
__global__ __launch_bounds__(256) void k_fc_out(
    const bf16* __restrict__ Hhi, const bf16* __restrict__ Hlo,
    const bf16* __restrict__ Whi, const bf16* __restrict__ Wlo,
    const float* __restrict__ b_fc, const float* __restrict__ partial,
    float* __restrict__ out)
{
    __shared__ float invs[128];
    const int tid  = threadIdx.x;
    const int lane = tid & 63;
    const int wid  = tid >> 6;
    const int tg   = blockIdx.x / NV2;
    const int nv   = blockIdx.x % NV2;
    const int t0   = tg * 128 + wid * 32;
    const int lr   = lane & 15, lq = lane >> 4;

    if (tid < 128) {
        const long tk = (long)tg * 128 + tid;
        float s = 0.0f;
        #pragma unroll
        for (int q = 0; q < NV1; ++q) s += partial[(long)q * NTOK + tk];
        invs[tid] = 1.0f / s;
    }

    const long arow0 = (long)(t0 + lr) * D_H + lq * 8;
    const long arow1 = arow0 + 16 * D_H;
    bf16x8 a0h = *(const bf16x8*)(Hhi + arow0);
    bf16x8 a0l = *(const bf16x8*)(Hlo + arow0);
    bf16x8 a1h = *(const bf16x8*)(Hhi + arow1);
    bf16x8 a1l = *(const bf16x8*)(Hlo + arow1);
    __syncthreads();

    float inv0[4], inv1[4];
    #pragma unroll
    for (int r = 0; r < 4; ++r) {
        inv0[r] = invs[wid * 32 + lq * 4 + r];
        inv1[r] = invs[wid * 32 + 16 + lq * 4 + r];
    }

    const f32x4 z = {0.f, 0.f, 0.f, 0.f};
    int v0 = nv * (VOCAB / NV2);
    for (int tile = 0; tile < VT2; ++tile, v0 += 16) {
        const long brow = (long)(v0 + lr) * D_H + lq * 8;
        bf16x8 bh = *(const bf16x8*)(Whi + brow);
        bf16x8 bl = *(const bf16x8*)(Wlo + brow);
        float bias = b_fc[v0 + lr];
        f32x4 d0 = __builtin_amdgcn_mfma_f32_16x16x32_bf16(a0h, bh, z, 0, 0, 0);
        d0 = __builtin_amdgcn_mfma_f32_16x16x32_bf16(a0l, bh, d0, 0, 0, 0);
        d0 = __builtin_amdgcn_mfma_f32_16x16x32_bf16(a0h, bl, d0, 0, 0, 0);
        f32x4 d1 = __builtin_amdgcn_mfma_f32_16x16x32_bf16(a1h, bh, z, 0, 0, 0);
        d1 = __builtin_amdgcn_mfma_f32_16x16x32_bf16(a1l, bh, d1, 0, 0, 0);
        d1 = __builtin_amdgcn_mfma_f32_16x16x32_bf16(a1h, bl, d1, 0, 0, 0);
        const int vcol = v0 + lr;
        #pragma unroll
        for (int r = 0; r < 4; ++r) {
            out[(long)(t0 + lq * 4 + r) * VOCAB + vcol] =
                __expf(d0[r] + bias) * inv0[r];
            out[(long)(t0 + 16 + lq * 4 + r) * VOCAB + vcol] =
                __expf(d1[r] + bias) * inv1[r];
        }
    }
}

// ---------------------------------------------------------------------------
extern "C" void kernel_launch(void* const* d_in, const int* in_sizes, int n_in,
                              void* d_out, int out_size, void* d_ws, size_t ws_size,
                              hipStream_t stream)
{
    const int*   x_ids = (const int*)d_in[0];
    const float* emb   = (const float*)d_in[1];
    const float* W_ih1 = (const float*)d_in[2];
    const float* W_hh1 = (const float*)d_in[3];
    const float* b_ih1 = (const float*)d_in[4];
    const float* b_hh1 = (const float*)d_in[5];
    const float* W_ih2 = (const float*)d_in[6];
    const float* W_hh2 = (const float*)d_in[7];
    const float* b_ih2 = (const float*)d_in[8];
    const float* b_hh2 = (const float*)d_in[9];
    const float* W_fc  = (const float*)d_in[10];
    const float* b_fc  = (const float*)d_in[11];
    float* out = (float*)d_out;

    char* p = (char*)d_ws;
    float* G1d     = (float*)p;            p += (long)S_LEN * 8 * 64 * 4 * 4; // 4 MB
    bf16* Hhi      = (bf16*)p;             p += (long)NTOK * D_H * 2;   // 512 KB
    bf16* Hlo      = (bf16*)p;             p += (long)NTOK * D_H * 2;   // 512 KB
    bf16* Whi      = (bf16*)p;             p += (long)VOCAB * D_H * 2;  // 2 MB
    bf16* Wlo      = (bf16*)p;             p += (long)VOCAB * D_H * 2;  // 2 MB
    float* partial = (float*)p;            p += (long)NV1 * NTOK * 4;   // 800 KB

    k_embed_cvt<<<EMB_BLKS + CVT_BLKS, 128, 0, stream>>>(
        x_ids, emb, W_ih1, b_ih1, b_hh1, G1d, W_fc, Whi, Wlo);
    k_lstm_mfma<<<1, 512, 0, stream>>>(G1d, W_hh1, W_ih2, W_hh2, b_ih2, b_hh2, Hhi, Hlo);
    k_fc_sum<<<(NTOK / 128) * NV1, 256, 0, stream>>>(Hhi, Hlo, Whi, Wlo, b_fc, partial);
    k_fc_out<<<(NTOK / 128) * NV2, 256, 0, stream>>>(Hhi, Hlo, Whi, Wlo, b_fc, partial, out);
}

// Round 21
// 664.455 us; speedup vs baseline: 1.0023x; 1.0023x over previous
//
#include <hip/hip_runtime.h>
#include <math.h>

#define VOCAB 32000
#define D_IN  256
#define D_H   32
#define B_SZ  16
#define S_LEN 512
#define NTOK  (B_SZ * S_LEN)   // 8192
#define NV1   25               // vocab splits in sum pass
#define VT1   (VOCAB / 16 / NV1)   // 80 tiles of 16 rows
#define NV2   25               // vocab splits in out pass
#define VT2   (VOCAB / 16 / NV2)   // 80 tiles
#define EMB_BLKS (NTOK / 4)            // 2048
#define CVT_BLKS (VOCAB * D_H / 512)   // 2000

typedef __bf16 bf16;
typedef __attribute__((ext_vector_type(8))) __bf16 bf16x8;
typedef __attribute__((ext_vector_type(4))) __bf16 bf16x4;
typedef __attribute__((ext_vector_type(4))) float f32x4;

__device__ __forceinline__ float rcpf(float x) {
    return __builtin_amdgcn_rcpf(x);
}

__device__ __forceinline__ float sigf(float x) {
    return rcpf(1.0f + __expf(-x));
}

__device__ __forceinline__ float tanhfast(float x) {
    float ax = fabsf(x);
    float e = __expf(-2.0f * ax);
    float r = (1.0f - e) * rcpf(1.0f + e);
    return copysignf(r, x);
}

__device__ __forceinline__ float dot4(float4 a, float4 b) {
    return a.x * b.x + a.y * b.y + a.z * b.z + a.w * b.w;
}

// ---------------------------------------------------------------------------
// Kernel A (merged): blocks [0, EMB_BLKS) = input-gate pack;
// blocks [EMB_BLKS, EMB_BLKS+CVT_BLKS) = W_fc -> bf16 hi/lo split.
// ---------------------------------------------------------------------------
__global__ __launch_bounds__(128) void k_embed_cvt(
    const int* __restrict__ x_ids, const float* __restrict__ emb,
    const float* __restrict__ W_ih1, const float* __restrict__ b_ih1,
    const float* __restrict__ b_hh1, float* __restrict__ G1d,
    const float* __restrict__ W_fc, bf16* __restrict__ Whi,
    bf16* __restrict__ Wlo)
{
    if (blockIdx.x >= EMB_BLKS) {
        const long i = ((long)(blockIdx.x - EMB_BLKS) * 128 + threadIdx.x) * 4;
        float4 w = *(const float4*)(W_fc + i);
        bf16 h0 = (bf16)w.x, h1 = (bf16)w.y, h2 = (bf16)w.z, h3 = (bf16)w.w;
        bf16x4 hv = {h0, h1, h2, h3};
        bf16x4 lv = {(bf16)(w.x - (float)h0), (bf16)(w.y - (float)h1),
                     (bf16)(w.z - (float)h2), (bf16)(w.w - (float)h3)};
        *(bf16x4*)(Whi + i) = hv;
        *(bf16x4*)(Wlo + i) = lv;
        return;
    }

    __shared__ float4 xs[4][64];
    const int tid = threadIdx.x;
    const int t0  = blockIdx.x * 4;
    const int r0  = tid >> 6, j = tid & 63;
    #pragma unroll
    for (int rr = 0; rr < 2; ++rr) {
        int r = rr * 2 + r0;
        long id = x_ids[t0 + r];
        xs[r][j] = ((const float4*)(emb + id * (long)D_IN))[j];
    }
    __syncthreads();

    const int g = tid;
    const float4* wrow = (const float4*)(W_ih1 + (long)g * D_IN);
    const float bias = b_ih1[g] + b_hh1[g];
    float a0 = bias, a1 = bias, a2 = bias, a3 = bias;
    #pragma unroll 8
    for (int jj = 0; jj < 64; ++jj) {
        float4 w = wrow[jj];
        a0 += dot4(w, xs[0][jj]);
        a1 += dot4(w, xs[1][jj]);
        a2 += dot4(w, xs[2][jj]);
        a3 += dot4(w, xs[3][jj]);
    }
    const int b  = t0 >> 9;
    const int s0 = t0 & 511;
    const int gt = g >> 5;
    const int u  = g & 31;
    const int w  = u >> 2;
    const int lq = u & 3;
    const int lane = lq * 16 + b;
    float vals[4] = {a0, a1, a2, a3};
    #pragma unroll
    for (int k = 0; k < 4; ++k) {
        G1d[(((long)(s0 + k) * 8 + w) * 64 + lane) * 4 + gt] = vals[k];
    }
}

// ---------------------------------------------------------------------------
// Kernel B: MFMA LSTM v6 (R19-best): 3 MFMAs/step, bf16 recurrence,
// plain __syncthreads barriers, chunked G1 register staging, LDS ring
// flushed every 16 steps. Stored h2 keeps full hi/lo precision.
// ---------------------------------------------------------------------------
__global__ __launch_bounds__(512, 1) void k_lstm_mfma(
    const float* __restrict__ G1d,
    const float* __restrict__ W_hh1,
    const float* __restrict__ W_ih2, const float* __restrict__ W_hh2,
    const float* __restrict__ b_ih2, const float* __restrict__ b_hh2,
    bf16* __restrict__ Hhi, bf16* __restrict__ Hlo)
{
    __shared__ alignas(16) bf16 H1h[2][16][40];
    __shared__ alignas(16) bf16 H2h[2][16][40];
    __shared__ alignas(16) float ring[2][16][16][36];   // 72 KB

    const int t  = threadIdx.x;
    const int w  = t >> 6;
    const int l  = t & 63;
    const int lr = l & 15, lq = l >> 4;

    const int garow = (lr & 3) * 32 + 4 * w + (lr >> 2);
    bf16x8 w1h, wi2h, wh2h;
    #pragma unroll
    for (int j = 0; j < 8; ++j) {
        w1h[j]  = (bf16)W_hh1[garow * D_H + lq * 8 + j];
        wi2h[j] = (bf16)W_ih2[garow * D_H + lq * 8 + j];
        wh2h[j] = (bf16)W_hh2[garow * D_H + lq * 8 + j];
    }

    const int u = 4 * w + lq;      // this lane's cell unit; batch = lr
    f32x4 bias2;
    #pragma unroll
    for (int r = 0; r < 4; ++r)
        bias2[r] = b_ih2[r * 32 + u] + b_hh2[r * 32 + u];

    bf16x8 h1fh, h2fh;
    #pragma unroll
    for (int j = 0; j < 8; ++j) {
        h1fh[j] = (bf16)0.0f; h2fh[j] = (bf16)0.0f;
    }
    float c1 = 0.0f, c2 = 0.0f;

    const f32x4* G1v = (const f32x4*)G1d;

    // flush chunk cc (steps 16cc..16cc+15) from ring to Hhi/Hlo as hi/lo bf16
    auto flush_chunk = [&](int cc) {
        const int rp   = cc & 1;
        const int pair = t >> 1;
        const int ss   = pair >> 4;
        const int bb   = pair & 15;
        const int u0   = (t & 1) * 16;
        const float* src = &ring[rp][ss][bb][u0];
        const long gbase = ((long)bb * S_LEN + cc * 16 + ss) * D_H + u0;
        #pragma unroll
        for (int q = 0; q < 4; ++q) {
            float4 v = *(const float4*)(src + q * 4);
            bf16 e0 = (bf16)v.x, e1 = (bf16)v.y, e2 = (bf16)v.z, e3 = (bf16)v.w;
            bf16x4 hv = {e0, e1, e2, e3};
            bf16x4 lv = {(bf16)(v.x - (float)e0), (bf16)(v.y - (float)e1),
                         (bf16)(v.z - (float)e2), (bf16)(v.w - (float)e3)};
            *(bf16x4*)(Hhi + gbase + q * 4) = hv;
            *(bf16x4*)(Hlo + gbase + q * 4) = lv;
        }
    };

    // one LSTM step: L1(s) + L2(s-1), 1 barrier, 3 MFMAs
    auto step = [&](int s, f32x4 g1c) {
        f32x4 d = __builtin_amdgcn_mfma_f32_16x16x32_bf16(w1h, h1fh, g1c, 0, 0, 0);

        f32x4 e;
        if (s > 0) {
            e = __builtin_amdgcn_mfma_f32_16x16x32_bf16(wi2h, h1fh, bias2, 0, 0, 0);
            e = __builtin_amdgcn_mfma_f32_16x16x32_bf16(wh2h, h2fh, e, 0, 0, 0);
        }

        {
            float iv = sigf(d[0]), fv = sigf(d[1]);
            float gv = tanhfast(d[2]), ov = sigf(d[3]);
            c1 = fv * c1 + iv * gv;
            float h1 = ov * tanhfast(c1);
            H1h[s & 1][lr][u] = (bf16)h1;
        }

        if (s > 0) {
            float iv = sigf(e[0]), fv = sigf(e[1]);
            float gv = tanhfast(e[2]), ov = sigf(e[3]);
            c2 = fv * c2 + iv * gv;
            float h2 = ov * tanhfast(c2);
            H2h[(s - 1) & 1][lr][u] = (bf16)h2;
            ring[((s - 1) >> 4) & 1][(s - 1) & 15][lr][u] = h2;
        }
        __syncthreads();

        h1fh = *(const bf16x8*)&H1h[s & 1][lr][lq * 8];
        if (s > 0) {
            h2fh = *(const bf16x8*)&H2h[(s - 1) & 1][lr][lq * 8];
        }

        if ((s & 15) == 0 && s > 0) {
            flush_chunk((s >> 4) - 1);
        }
    };

    // ---- chunked G1 staging: 64 chunks of 8 steps, double-buffered ----
    f32x4 bufA[8], bufB[8];
    #pragma unroll
    for (int k = 0; k < 8; ++k)
        bufA[k] = G1v[((long)k * 8 + w) * 64 + l];

    #pragma unroll 1
    for (int c = 0; c < 64; c += 2) {
        {   // even chunk: compute from bufA, prefetch chunk c+1 into bufB
            const int cn = c + 1;
            #pragma unroll
            for (int k = 0; k < 8; ++k)
                bufB[k] = G1v[((long)(cn * 8 + k) * 8 + w) * 64 + l];
            #pragma unroll
            for (int k = 0; k < 8; ++k)
                step(c * 8 + k, bufA[k]);
        }
        {   // odd chunk: compute from bufB, prefetch chunk c+2 into bufA
            const int cn = (c + 2 < 64) ? c + 2 : 0;
            #pragma unroll
            for (int k = 0; k < 8; ++k)
                bufA[k] = G1v[((long)(cn * 8 + k) * 8 + w) * 64 + l];
            #pragma unroll
            for (int k = 0; k < 8; ++k)
                step((c + 1) * 8 + k, bufB[k]);
        }
    }

    // ---- epilogue: L2(S_LEN-1) ----
    {
        f32x4 e = __builtin_amdgcn_mfma_f32_16x16x32_bf16(wi2h, h1fh, bias2, 0, 0, 0);
        e = __builtin_amdgcn_mfma_f32_16x16x32_bf16(wh2h, h2fh, e, 0, 0, 0);
        float iv = sigf(e[0]), fv = sigf(e[1]);
        float gv = tanhfast(e[2]), ov = sigf(e[3]);
        c2 = fv * c2 + iv * gv;
        float h2 = ov * tanhfast(c2);
        ring[((S_LEN - 1) >> 4) & 1][(S_LEN - 1) & 15][lr][u] = h2;
    }
    __syncthreads();
    flush_chunk((S_LEN >> 4) - 1);       // steps 496..511
}

// ---------------------------------------------------------------------------
// Kernel C1 (MFMA): partial softmax denominators.
// ---------------------------------------------------------------------------
__global__ __launch_bounds__(256) void k_fc_sum(
    const bf16* __restrict__ Hhi, const bf16* __restrict__ Hlo,
    const bf16* __restrict__ Whi, const bf16* __restrict__ Wlo,
    const float* __restrict__ b_fc, float* __restrict__ partial)
{
    const int lane = threadIdx.x & 63;
    const int wid  = threadIdx.x >> 6;
    const int tg   = blockIdx.x / NV1;
    const int nv   = blockIdx.x % NV1;
    const int t0   = tg * 128 + wid * 32;
    const int lr   = lane & 15, lq = lane >> 4;

    const long arow0 = (long)(t0 + lr) * D_H + lq * 8;
    const long arow1 = arow0 + 16 * D_H;
    bf16x8 a0h = *(const bf16x8*)(Hhi + arow0);
    bf16x8 a0l = *(const bf16x8*)(Hlo + arow0);
    bf16x8 a1h = *(const bf16x8*)(Hhi + arow1);
    bf16x8 a1l = *(const bf16x8*)(Hlo + arow1);

    f32x4 acc0 = {0.f, 0.f, 0.f, 0.f}, acc1 = {0.f, 0.f, 0.f, 0.f};
    const f32x4 z = {0.f, 0.f, 0.f, 0.f};
    int v0 = nv * (VOCAB / NV1);
    for (int tile = 0; tile < VT1; ++tile, v0 += 16) {
        const long brow = (long)(v0 + lr) * D_H + lq * 8;
        bf16x8 bh = *(const bf16x8*)(Whi + brow);
        bf16x8 bl = *(const bf16x8*)(Wlo + brow);
        float bias = b_fc[v0 + lr];
        f32x4 d0 = __builtin_amdgcn_mfma_f32_16x16x32_bf16(a0h, bh, z, 0, 0, 0);
        d0 = __builtin_amdgcn_mfma_f32_16x16x32_bf16(a0l, bh, d0, 0, 0, 0);
        d0 = __builtin_amdgcn_mfma_f32_16x16x32_bf16(a0h, bl, d0, 0, 0, 0);
        f32x4 d1 = __builtin_amdgcn_mfma_f32_16x16x32_bf16(a1h, bh, z, 0, 0, 0);
        d1 = __builtin_amdgcn_mfma_f32_16x16x32_bf16(a1l, bh, d1, 0, 0, 0);
        d1 = __builtin_amdgcn_mfma_f32_16x16x32_bf16(a1h, bl, d1, 0, 0, 0);
        #pragma unroll
        for (int r = 0; r < 4; ++r) {
            acc0[r] += __expf(d0[r] + bias);
            acc1[r] += __expf(d1[r] + bias);
        }
    }

    #pragma unroll
    for (int m = 1; m < 16; m <<= 1) {
        #pragma unroll
        for (int r = 0; r < 4; ++r) {
            acc0[r] += __shfl_xor(acc0[r], m, 64);
            acc1[r] += __shfl_xor(acc1[r], m, 64);
        }
    }
    if (lr == 0) {
        #pragma unroll
        for (int r = 0; r < 4; ++r) {
            partial[(long)nv * NTOK + t0 + lq * 4 + r]      = acc0[r];
            partial[(long)nv * NTOK + t0 + 16 + lq * 4 + r] = acc1[r];
        }
    }
}

// ---------------------------------------------------------------------------
// Kernel C2 (MFMA): recompute logits, write normalized softmax.
// Per-token 1/sum is recomputed from `partial` in-block (k_inv removed).
// ---------------------------------------------------------------------------
__global__ __launch_bounds__(256) void k_fc_out(
    const bf16* __restrict__ Hhi, const bf16* __restrict__ Hlo,
    const bf16* __restrict__ Whi, const bf16* __restrict__ Wlo,
    const float* __restrict__ b_fc, const float* __restrict__ partial,
    float* __restrict__ out)
{
    __shared__ float invs[128];
    const int tid  = threadIdx.x;
    const int lane = tid & 63;
    const int wid  = tid >> 6;
    const int tg   = blockIdx.x / NV2;
    const int nv   = blockIdx.x % NV2;
    const int t0   = tg * 128 + wid * 32;
    const int lr   = lane & 15, lq = lane >> 4;

    if (tid < 128) {
        const long tk = (long)tg * 128 + tid;
        float s = 0.0f;
        #pragma unroll
        for (int q = 0; q < NV1; ++q) s += partial[(long)q * NTOK + tk];
        invs[tid] = 1.0f / s;
    }

    const long arow0 = (long)(t0 + lr) * D_H + lq * 8;
    const long arow1 = arow0 + 16 * D_H;
    bf16x8 a0h = *(const bf16x8*)(Hhi + arow0);
    bf16x8 a0l = *(const bf16x8*)(Hlo + arow0);
    bf16x8 a1h = *(const bf16x8*)(Hhi + arow1);
    bf16x8 a1l = *(const bf16x8*)(Hlo + arow1);
    __syncthreads();

    float inv0[4], inv1[4];
    #pragma unroll
    for (int r = 0; r < 4; ++r) {
        inv0[r] = invs[wid * 32 + lq * 4 + r];
        inv1[r] = invs[wid * 32 + 16 + lq * 4 + r];
    }

    const f32x4 z = {0.f, 0.f, 0.f, 0.f};
    int v0 = nv * (VOCAB / NV2);
    for (int tile = 0; tile < VT2; ++tile, v0 += 16) {
        const long brow = (long)(v0 + lr) * D_H + lq * 8;
        bf16x8 bh = *(const bf16x8*)(Whi + brow);
        bf16x8 bl = *(const bf16x8*)(Wlo + brow);
        float bias = b_fc[v0 + lr];
        f32x4 d0 = __builtin_amdgcn_mfma_f32_16x16x32_bf16(a0h, bh, z, 0, 0, 0);
        d0 = __builtin_amdgcn_mfma_f32_16x16x32_bf16(a0l, bh, d0, 0, 0, 0);
        d0 = __builtin_amdgcn_mfma_f32_16x16x32_bf16(a0h, bl, d0, 0, 0, 0);
        f32x4 d1 = __builtin_amdgcn_mfma_f32_16x16x32_bf16(a1h, bh, z, 0, 0, 0);
        d1 = __builtin_amdgcn_mfma_f32_16x16x32_bf16(a1l, bh, d1, 0, 0, 0);
        d1 = __builtin_amdgcn_mfma_f32_16x16x32_bf16(a1h, bl, d1, 0, 0, 0);
        const int vcol = v0 + lr;
        #pragma unroll
        for (int r = 0; r < 4; ++r) {
            out[(long)(t0 + lq * 4 + r) * VOCAB + vcol] =
                __expf(d0[r] + bias) * inv0[r];
            out[(long)(t0 + 16 + lq * 4 + r) * VOCAB + vcol] =
                __expf(d1[r] + bias) * inv1[r];
        }
    }
}

// ---------------------------------------------------------------------------
extern "C" void kernel_launch(void* const* d_in, const int* in_sizes, int n_in,
                              void* d_out, int out_size, void* d_ws, size_t ws_size,
                              hipStream_t stream)
{
    const int*   x_ids = (const int*)d_in[0];
    const float* emb   = (const float*)d_in[1];
    const float* W_ih1 = (const float*)d_in[2];
    const float* W_hh1 = (const float*)d_in[3];
    const float* b_ih1 = (const float*)d_in[4];
    const float* b_hh1 = (const float*)d_in[5];
    const float* W_ih2 = (const float*)d_in[6];
    const float* W_hh2 = (const float*)d_in[7];
    const float* b_ih2 = (const float*)d_in[8];
    const float* b_hh2 = (const float*)d_in[9];
    const float* W_fc  = (const float*)d_in[10];
    const float* b_fc  = (const float*)d_in[11];
    float* out = (float*)d_out;

    char* p = (char*)d_ws;
    float* G1d     = (float*)p;            p += (long)S_LEN * 8 * 64 * 4 * 4; // 4 MB
    bf16* Hhi      = (bf16*)p;             p += (long)NTOK * D_H * 2;   // 512 KB
    bf16* Hlo      = (bf16*)p;             p += (long)NTOK * D_H * 2;   // 512 KB
    bf16* Whi      = (bf16*)p;             p += (long)VOCAB * D_H * 2;  // 2 MB
    bf16* Wlo      = (bf16*)p;             p += (long)VOCAB * D_H * 2;  // 2 MB
    float* partial = (float*)p;            p += (long)NV1 * NTOK * 4;   // 800 KB

    k_embed_cvt<<<EMB_BLKS + CVT_BLKS, 128, 0, stream>>>(
        x_ids, emb, W_ih1, b_ih1, b_hh1, G1d, W_fc, Whi, Wlo);
    k_lstm_mfma<<<1, 512, 0, stream>>>(G1d, W_hh1, W_ih2, W_hh2, b_ih2, b_hh2, Hhi, Hlo);
    k_fc_sum<<<(NTOK / 128) * NV1, 256, 0, stream>>>(Hhi, Hlo, Whi, Wlo, b_fc, partial);
    k_fc_out<<<(NTOK / 128) * NV2, 256, 0, stream>>>(Hhi, Hlo, Whi, Wlo, b_fc, partial, out);
}

// Round 22
// 636.432 us; speedup vs baseline: 1.0465x; 1.0440x over previous
//
#include <hip/hip_runtime.h>
#include <math.h>

#define VOCAB 32000
#define D_IN  256
#define D_H   32
#define B_SZ  16
#define S_LEN 512
#define NTOK  (B_SZ * S_LEN)   // 8192
#define NV1   25               // vocab splits in sum pass
#define VT1   (VOCAB / 16 / NV1)   // 80 tiles of 16 rows
#define NV2   25               // vocab splits in out pass
#define VT2   (VOCAB / 16 / NV2)   // 80 tiles

typedef __bf16 bf16;
typedef __attribute__((ext_vector_type(8))) __bf16 bf16x8;
typedef __attribute__((ext_vector_type(4))) __bf16 bf16x4;
typedef __attribute__((ext_vector_type(4))) float f32x4;

__device__ __forceinline__ float rcpf(float x) {
    return __builtin_amdgcn_rcpf(x);
}

__device__ __forceinline__ float sigf(float x) {
    return rcpf(1.0f + __expf(-x));
}

__device__ __forceinline__ float tanhfast(float x) {
    float ax = fabsf(x);
    float e = __expf(-2.0f * ax);
    float r = (1.0f - e) * rcpf(1.0f + e);
    return copysignf(r, x);
}

__device__ __forceinline__ float dot4(float4 a, float4 b) {
    return a.x * b.x + a.y * b.y + a.z * b.z + a.w * b.w;
}

// ---------------------------------------------------------------------------
// Convert W_fc (f32 [32000][32]) to bf16 hi/lo split arrays.
// ---------------------------------------------------------------------------
__global__ __launch_bounds__(256) void k_cvt_w(
    const float* __restrict__ W, bf16* __restrict__ Whi, bf16* __restrict__ Wlo)
{
    const long i = ((long)blockIdx.x * 256 + threadIdx.x) * 4;
    float4 w = *(const float4*)(W + i);
    bf16 h0 = (bf16)w.x, h1 = (bf16)w.y, h2 = (bf16)w.z, h3 = (bf16)w.w;
    bf16 l0 = (bf16)(w.x - (float)h0), l1 = (bf16)(w.y - (float)h1);
    bf16 l2 = (bf16)(w.z - (float)h2), l3 = (bf16)(w.w - (float)h3);
    bf16x4 hv = {h0, h1, h2, h3}, lv = {l0, l1, l2, l3};
    *(bf16x4*)(Whi + i) = hv;
    *(bf16x4*)(Wlo + i) = lv;
}

// ---------------------------------------------------------------------------
// Kernel A: input gates packed into the LSTM's D/C-fragment order (v2):
// float index (((s*8 + w)*64 + lane)*4 + gt), lane = lq*16 + b,
// holds G1[b][s][g = gt*32 + 4w + lq].
// ---------------------------------------------------------------------------
__global__ __launch_bounds__(128) void k_embed_gates(
    const int* __restrict__ x_ids, const float* __restrict__ emb,
    const float* __restrict__ W_ih1, const float* __restrict__ b_ih1,
    const float* __restrict__ b_hh1, float* __restrict__ G1d)
{
    __shared__ float4 xs[4][64];
    const int tid = threadIdx.x;
    const int t0  = blockIdx.x * 4;
    const int r0  = tid >> 6, j = tid & 63;
    #pragma unroll
    for (int rr = 0; rr < 2; ++rr) {
        int r = rr * 2 + r0;
        long id = x_ids[t0 + r];
        xs[r][j] = ((const float4*)(emb + id * (long)D_IN))[j];
    }
    __syncthreads();

    const int g = tid;
    const float4* wrow = (const float4*)(W_ih1 + (long)g * D_IN);
    const float bias = b_ih1[g] + b_hh1[g];
    float a0 = bias, a1 = bias, a2 = bias, a3 = bias;
    #pragma unroll 8
    for (int jj = 0; jj < 64; ++jj) {
        float4 w = wrow[jj];
        a0 += dot4(w, xs[0][jj]);
        a1 += dot4(w, xs[1][jj]);
        a2 += dot4(w, xs[2][jj]);
        a3 += dot4(w, xs[3][jj]);
    }
    const int b  = t0 >> 9;
    const int s0 = t0 & 511;
    const int gt = g >> 5;
    const int u  = g & 31;
    const int w  = u >> 2;
    const int lq = u & 3;
    const int lane = lq * 16 + b;
    float vals[4] = {a0, a1, a2, a3};
    #pragma unroll
    for (int k = 0; k < 4; ++k) {
        G1d[(((long)(s0 + k) * 8 + w) * 64 + lane) * 4 + gt] = vals[k];
    }
}

// ---------------------------------------------------------------------------
// Kernel B: MFMA LSTM v6: 3 MFMAs/step (L1: 1, L2: 2-deep chain), bf16
// recurrence, plain __syncthreads, chunked G1 register staging (8 steps,
// double-buffered), LDS ring flushed every 16 steps. Stored h2 keeps full
// hi/lo precision for the fc passes.
// ---------------------------------------------------------------------------
__global__ __launch_bounds__(512, 1) void k_lstm_mfma(
    const float* __restrict__ G1d,
    const float* __restrict__ W_hh1,
    const float* __restrict__ W_ih2, const float* __restrict__ W_hh2,
    const float* __restrict__ b_ih2, const float* __restrict__ b_hh2,
    bf16* __restrict__ Hhi, bf16* __restrict__ Hlo)
{
    __shared__ alignas(16) bf16 H1h[2][16][40];
    __shared__ alignas(16) bf16 H2h[2][16][40];
    __shared__ alignas(16) float ring[2][16][16][36];   // 72 KB

    const int t  = threadIdx.x;
    const int w  = t >> 6;
    const int l  = t & 63;
    const int lr = l & 15, lq = l >> 4;

    const int garow = (lr & 3) * 32 + 4 * w + (lr >> 2);
    bf16x8 w1h, wi2h, wh2h;
    #pragma unroll
    for (int j = 0; j < 8; ++j) {
        w1h[j]  = (bf16)W_hh1[garow * D_H + lq * 8 + j];
        wi2h[j] = (bf16)W_ih2[garow * D_H + lq * 8 + j];
        wh2h[j] = (bf16)W_hh2[garow * D_H + lq * 8 + j];
    }

    const int u = 4 * w + lq;      // this lane's cell unit; batch = lr
    f32x4 bias2;
    #pragma unroll
    for (int r = 0; r < 4; ++r)
        bias2[r] = b_ih2[r * 32 + u] + b_hh2[r * 32 + u];

    bf16x8 h1fh, h2fh;
    #pragma unroll
    for (int j = 0; j < 8; ++j) {
        h1fh[j] = (bf16)0.0f; h2fh[j] = (bf16)0.0f;
    }
    float c1 = 0.0f, c2 = 0.0f;

    const f32x4* G1v = (const f32x4*)G1d;

    // flush chunk cc (steps 16cc..16cc+15) from ring to Hhi/Hlo as hi/lo bf16
    auto flush_chunk = [&](int cc) {
        const int rp   = cc & 1;
        const int pair = t >> 1;
        const int ss   = pair >> 4;
        const int bb   = pair & 15;
        const int u0   = (t & 1) * 16;
        const float* src = &ring[rp][ss][bb][u0];
        const long gbase = ((long)bb * S_LEN + cc * 16 + ss) * D_H + u0;
        #pragma unroll
        for (int q = 0; q < 4; ++q) {
            float4 v = *(const float4*)(src + q * 4);
            bf16 e0 = (bf16)v.x, e1 = (bf16)v.y, e2 = (bf16)v.z, e3 = (bf16)v.w;
            bf16x4 hv = {e0, e1, e2, e3};
            bf16x4 lv = {(bf16)(v.x - (float)e0), (bf16)(v.y - (float)e1),
                         (bf16)(v.z - (float)e2), (bf16)(v.w - (float)e3)};
            *(bf16x4*)(Hhi + gbase + q * 4) = hv;
            *(bf16x4*)(Hlo + gbase + q * 4) = lv;
        }
    };

    // one LSTM step: L1(s) + L2(s-1), 1 barrier, 3 MFMAs
    auto step = [&](int s, f32x4 g1c) {
        f32x4 d = __builtin_amdgcn_mfma_f32_16x16x32_bf16(w1h, h1fh, g1c, 0, 0, 0);

        f32x4 e;
        if (s > 0) {
            e = __builtin_amdgcn_mfma_f32_16x16x32_bf16(wi2h, h1fh, bias2, 0, 0, 0);
            e = __builtin_amdgcn_mfma_f32_16x16x32_bf16(wh2h, h2fh, e, 0, 0, 0);
        }

        {
            float iv = sigf(d[0]), fv = sigf(d[1]);
            float gv = tanhfast(d[2]), ov = sigf(d[3]);
            c1 = fv * c1 + iv * gv;
            float h1 = ov * tanhfast(c1);
            H1h[s & 1][lr][u] = (bf16)h1;
        }

        if (s > 0) {
            float iv = sigf(e[0]), fv = sigf(e[1]);
            float gv = tanhfast(e[2]), ov = sigf(e[3]);
            c2 = fv * c2 + iv * gv;
            float h2 = ov * tanhfast(c2);
            H2h[(s - 1) & 1][lr][u] = (bf16)h2;
            ring[((s - 1) >> 4) & 1][(s - 1) & 15][lr][u] = h2;
        }
        __syncthreads();

        h1fh = *(const bf16x8*)&H1h[s & 1][lr][lq * 8];
        if (s > 0) {
            h2fh = *(const bf16x8*)&H2h[(s - 1) & 1][lr][lq * 8];
        }

        if ((s & 15) == 0 && s > 0) {
            flush_chunk((s >> 4) - 1);
        }
    };

    // ---- chunked G1 staging: 64 chunks of 8 steps, double-buffered ----
    f32x4 bufA[8], bufB[8];
    #pragma unroll
    for (int k = 0; k < 8; ++k)
        bufA[k] = G1v[((long)k * 8 + w) * 64 + l];

    #pragma unroll 1
    for (int c = 0; c < 64; c += 2) {
        {   // even chunk: compute from bufA, prefetch chunk c+1 into bufB
            const int cn = c + 1;
            #pragma unroll
            for (int k = 0; k < 8; ++k)
                bufB[k] = G1v[((long)(cn * 8 + k) * 8 + w) * 64 + l];
            #pragma unroll
            for (int k = 0; k < 8; ++k)
                step(c * 8 + k, bufA[k]);
        }
        {   // odd chunk: compute from bufB, prefetch chunk c+2 into bufA
            const int cn = (c + 2 < 64) ? c + 2 : 0;
            #pragma unroll
            for (int k = 0; k < 8; ++k)
                bufA[k] = G1v[((long)(cn * 8 + k) * 8 + w) * 64 + l];
            #pragma unroll
            for (int k = 0; k < 8; ++k)
                step((c + 1) * 8 + k, bufB[k]);
        }
    }

    // ---- epilogue: L2(S_LEN-1) ----
    {
        f32x4 e = __builtin_amdgcn_mfma_f32_16x16x32_bf16(wi2h, h1fh, bias2, 0, 0, 0);
        e = __builtin_amdgcn_mfma_f32_16x16x32_bf16(wh2h, h2fh, e, 0, 0, 0);
        float iv = sigf(e[0]), fv = sigf(e[1]);
        float gv = tanhfast(e[2]), ov = sigf(e[3]);
        c2 = fv * c2 + iv * gv;
        float h2 = ov * tanhfast(c2);
        ring[((S_LEN - 1) >> 4) & 1][(S_LEN - 1) & 15][lr][u] = h2;
    }
    __syncthreads();
    flush_chunk((S_LEN >> 4) - 1);       // steps 496..511
}

// ---------------------------------------------------------------------------
// Kernel C1 (MFMA): partial softmax denominators.
// ---------------------------------------------------------------------------
__global__ __launch_bounds__(256) void k_fc_sum(
    const bf16* __restrict__ Hhi, const bf16* __restrict__ Hlo,
    const bf16* __restrict__ Whi, const bf16* __restrict__ Wlo,
    const float* __restrict__ b_fc, float* __restrict__ partial)
{
    const int lane = threadIdx.x & 63;
    const int wid  = threadIdx.x >> 6;
    const int tg   = blockIdx.x / NV1;
    const int nv   = blockIdx.x % NV1;
    const int t0   = tg * 128 + wid * 32;
    const int lr   = lane & 15, lq = lane >> 4;

    const long arow0 = (long)(t0 + lr) * D_H + lq * 8;
    const long arow1 = arow0 + 16 * D_H;
    bf16x8 a0h = *(const bf16x8*)(Hhi + arow0);
    bf16x8 a0l = *(const bf16x8*)(Hlo + arow0);
    bf16x8 a1h = *(const bf16x8*)(Hhi + arow1);
    bf16x8 a1l = *(const bf16x8*)(Hlo + arow1);

    f32x4 acc0 = {0.f, 0.f, 0.f, 0.f}, acc1 = {0.f, 0.f, 0.f, 0.f};
    const f32x4 z = {0.f, 0.f, 0.f, 0.f};
    int v0 = nv * (VOCAB / NV1);
    for (int tile = 0; tile < VT1; ++tile, v0 += 16) {
        const long brow = (long)(v0 + lr) * D_H + lq * 8;
        bf16x8 bh = *(const bf16x8*)(Whi + brow);
        bf16x8 bl = *(const bf16x8*)(Wlo + brow);
        float bias = b_fc[v0 + lr];
        f32x4 d0 = __builtin_amdgcn_mfma_f32_16x16x32_bf16(a0h, bh, z, 0, 0, 0);
        d0 = __builtin_amdgcn_mfma_f32_16x16x32_bf16(a0l, bh, d0, 0, 0, 0);
        d0 = __builtin_amdgcn_mfma_f32_16x16x32_bf16(a0h, bl, d0, 0, 0, 0);
        f32x4 d1 = __builtin_amdgcn_mfma_f32_16x16x32_bf16(a1h, bh, z, 0, 0, 0);
        d1 = __builtin_amdgcn_mfma_f32_16x16x32_bf16(a1l, bh, d1, 0, 0, 0);
        d1 = __builtin_amdgcn_mfma_f32_16x16x32_bf16(a1h, bl, d1, 0, 0, 0);
        #pragma unroll
        for (int r = 0; r < 4; ++r) {
            acc0[r] += __expf(d0[r] + bias);
            acc1[r] += __expf(d1[r] + bias);
        }
    }

    #pragma unroll
    for (int m = 1; m < 16; m <<= 1) {
        #pragma unroll
        for (int r = 0; r < 4; ++r) {
            acc0[r] += __shfl_xor(acc0[r], m, 64);
            acc1[r] += __shfl_xor(acc1[r], m, 64);
        }
    }
    if (lr == 0) {
        #pragma unroll
        for (int r = 0; r < 4; ++r) {
            partial[(long)nv * NTOK + t0 + lq * 4 + r]      = acc0[r];
            partial[(long)nv * NTOK + t0 + 16 + lq * 4 + r] = acc1[r];
        }
    }
}

__global__ __launch_bounds__(256) void k_inv(
    const float* __restrict__ partial, float* __restrict__ inv_sum)
{
    const int t = blockIdx.x * 256 + threadIdx.x;
    float s = 0.0f;
    #pragma unroll
    for (int nv = 0; nv < NV1; ++nv) s += partial[(long)nv * NTOK + t];
    inv_sum[t] = 1.0f / s;
}

// ---------------------------------------------------------------------------
// Kernel C2 (MFMA): recompute logits, write normalized softmax.
// ---------------------------------------------------------------------------
__global__ __launch_bounds__(256) void k_fc_out(
    const bf16* __restrict__ Hhi, const bf16* __restrict__ Hlo,
    const bf16* __restrict__ Whi, const bf16* __restrict__ Wlo,
    const float* __restrict__ b_fc, const float* __restrict__ inv_sum,
    float* __restrict__ out)
{
    const int lane = threadIdx.x & 63;
    const int wid  = threadIdx.x >> 6;
    const int tg   = blockIdx.x / NV2;
    const int nv   = blockIdx.x % NV2;
    const int t0   = tg * 128 + wid * 32;
    const int lr   = lane & 15, lq = lane >> 4;

    const long arow0 = (long)(t0 + lr) * D_H + lq * 8;
    const long arow1 = arow0 + 16 * D_H;
    bf16x8 a0h = *(const bf16x8*)(Hhi + arow0);
    bf16x8 a0l = *(const bf16x8*)(Hlo + arow0);
    bf16x8 a1h = *(const bf16x8*)(Hhi + arow1);
    bf16x8 a1l = *(const bf16x8*)(Hlo + arow1);

    float inv0[4], inv1[4];
    #pragma unroll
    for (int r = 0; r < 4; ++r) {
        inv0[r] = inv_sum[t0 + lq * 4 + r];
        inv1[r] = inv_sum[t0 + 16 + lq * 4 + r];
    }

    const f32x4 z = {0.f, 0.f, 0.f, 0.f};
    int v0 = nv * (VOCAB / NV2);
    for (int tile = 0; tile < VT2; ++tile, v0 += 16) {
        const long brow = (long)(v0 + lr) * D_H + lq * 8;
        bf16x8 bh = *(const bf16x8*)(Whi + brow);
        bf16x8 bl = *(const bf16x8*)(Wlo + brow);
        float bias = b_fc[v0 + lr];
        f32x4 d0 = __builtin_amdgcn_mfma_f32_16x16x32_bf16(a0h, bh, z, 0, 0, 0);
        d0 = __builtin_amdgcn_mfma_f32_16x16x32_bf16(a0l, bh, d0, 0, 0, 0);
        d0 = __builtin_amdgcn_mfma_f32_16x16x32_bf16(a0h, bl, d0, 0, 0, 0);
        f32x4 d1 = __builtin_amdgcn_mfma_f32_16x16x32_bf16(a1h, bh, z, 0, 0, 0);
        d1 = __builtin_amdgcn_mfma_f32_16x16x32_bf16(a1l, bh, d1, 0, 0, 0);
        d1 = __builtin_amdgcn_mfma_f32_16x16x32_bf16(a1h, bl, d1, 0, 0, 0);
        const int vcol = v0 + lr;
        #pragma unroll
        for (int r = 0; r < 4; ++r) {
            out[(long)(t0 + lq * 4 + r) * VOCAB + vcol] =
                __expf(d0[r] + bias) * inv0[r];
            out[(long)(t0 + 16 + lq * 4 + r) * VOCAB + vcol] =
                __expf(d1[r] + bias) * inv1[r];
        }
    }
}

// ---------------------------------------------------------------------------
extern "C" void kernel_launch(void* const* d_in, const int* in_sizes, int n_in,
                              void* d_out, int out_size, void* d_ws, size_t ws_size,
                              hipStream_t stream)
{
    const int*   x_ids = (const int*)d_in[0];
    const float* emb   = (const float*)d_in[1];
    const float* W_ih1 = (const float*)d_in[2];
    const float* W_hh1 = (const float*)d_in[3];
    const float* b_ih1 = (const float*)d_in[4];
    const float* b_hh1 = (const float*)d_in[5];
    const float* W_ih2 = (const float*)d_in[6];
    const float* W_hh2 = (const float*)d_in[7];
    const float* b_ih2 = (const float*)d_in[8];
    const float* b_hh2 = (const float*)d_in[9];
    const float* W_fc  = (const float*)d_in[10];
    const float* b_fc  = (const float*)d_in[11];
    float* out = (float*)d_out;

    char* p = (char*)d_ws;
    float* G1d     = (float*)p;            p += (long)S_LEN * 8 * 64 * 4 * 4; // 4 MB
    bf16* Hhi      = (bf16*)p;             p += (long)NTOK * D_H * 2;   // 512 KB
    bf16* Hlo      = (bf16*)p;             p += (long)NTOK * D_H * 2;   // 512 KB
    bf16* Whi      = (bf16*)p;             p += (long)VOCAB * D_H * 2;  // 2 MB
    bf16* Wlo      = (bf16*)p;             p += (long)VOCAB * D_H * 2;  // 2 MB
    float* partial = (float*)p;            p += (long)NV1 * NTOK * 4;   // 800 KB
    float* inv_sum = (float*)p;            p += (long)NTOK * 4;         // 32 KB

    k_cvt_w<<<VOCAB * D_H / (256 * 4), 256, 0, stream>>>(W_fc, Whi, Wlo);
    k_embed_gates<<<NTOK / 4, 128, 0, stream>>>(x_ids, emb, W_ih1, b_ih1, b_hh1, G1d);
    k_lstm_mfma<<<1, 512, 0, stream>>>(G1d, W_hh1, W_ih2, W_hh2, b_ih2, b_hh2, Hhi, Hlo);
    k_fc_sum<<<(NTOK / 128) * NV1, 256, 0, stream>>>(Hhi, Hlo, Whi, Wlo, b_fc, partial);
    k_inv<<<NTOK / 256, 256, 0, stream>>>(partial, inv_sum);
    k_fc_out<<<(NTOK / 128) * NV2, 256, 0, stream>>>(Hhi, Hlo, Whi, Wlo, b_fc, inv_sum, out);
}